// Round 15
// baseline (43.180 us; speedup 1.0000x reference)
//
#include <hip/hip_runtime.h>
#include <hip/hip_bf16.h>

// NT-Xent loss, MI355X. B=4096, D=256, N=8192, temp=0.5.
// R15 = R14 (MX-fp4, 32-row waves, 4 waves/SIMD, full-step b[8] preload)
// + GRAM SYMMETRY HALVING: compute only 16x16 tiles with jtb >= itb.
// Upper tile exp sums feed row partials (rows itb..) AND col partials
// (= row sums of the skipped transpose tile, rows jtb..) -> MFMA, LDS and
// the exp pole (unshrinkable by dtype) all halve. R5's failed attempt was
// exposure-dominated bf16 + memset/tail overheads; here: 128x256 blocks ->
// 1056 upper-tri blocks ~= 1024 resident capacity (3% tail), NO memset
// (fin1 sums exactly the written slots: row slots bj>=i>>8, col slots
// bi<=2(i>>8)+1), and a block-uniform fast/slow split (94% strictly-upper
// blocks run the R14 loop + csum; 64 straddle blocks take per-rf checks).

typedef __attribute__((ext_vector_type(4))) float f32x4;
typedef __attribute__((ext_vector_type(8))) int i32x8;

#define N_TOT 8192
#define B_HALF 4096
#define D_DIM 256
#define NROWP 32   // row-partial slots: col panels (256 wide)
#define NCOLP 64   // col-partial slots: row blocks (128 tall)
#define NSTEP 4
#define NBLK 1056  // sum over bi<64 of (32 - bi/2)
#define SCL_PRE 1.6986436f             // sqrt((1/T)*log2 e)
#define RES_SCALE 0.6931471805599453f  // ln2: sim = acc * ln2 after prescale
#define S4 0x7B7B7B7B                  // E8M0 123 -> 2^-4 per operand

__device__ inline float fexp2(float x) {
#if __has_builtin(__builtin_amdgcn_exp2f)
  return __builtin_amdgcn_exp2f(x);
#else
  return exp2f(x);
#endif
}

// e2m1 encode, RNE against grid {0,.5,1,1.5,2,3,4,6}, clamp at 6
__device__ inline unsigned enc4(float v) {
  float av = fabsf(v);
  unsigned c = (av >= 0.25f) + (av >= 0.75f) + (av >= 1.25f) + (av >= 1.75f) +
               (av >= 2.5f) + (av >= 3.5f) + (av >= 5.0f);
  return c | ((v < 0.f) ? 8u : 0u);
}

__device__ inline i32x8 ld16z(const char* p) {
  int4 lo = *reinterpret_cast<const int4*>(p);
  i32x8 r = {lo.x, lo.y, lo.z, lo.w, 0, 0, 0, 0};  // fp4 uses low 4 regs
  return r;
}

__global__ __launch_bounds__(256) void nrm_kernel(const float* __restrict__ z1,
                                                  const float* __restrict__ z2,
                                                  unsigned short* __restrict__ zn4) {
  int row = blockIdx.x * 4 + (threadIdx.x >> 6);
  int lane = threadIdx.x & 63;
  const float* src = (row < B_HALF) ? (z1 + (size_t)row * D_DIM)
                                    : (z2 + (size_t)(row - B_HALF) * D_DIM);
  f32x4 v = *reinterpret_cast<const f32x4*>(src + lane * 4);
  float ss = v.x * v.x + v.y * v.y + v.z * v.z + v.w * v.w;
#pragma unroll
  for (int m = 32; m >= 1; m >>= 1) ss += __shfl_xor(ss, m);
  float inv = (SCL_PRE * 16.0f) / fmaxf(sqrtf(ss), 1e-8f);
  unsigned n0 = enc4(v.x * inv), n1 = enc4(v.y * inv);
  unsigned n2 = enc4(v.z * inv), n3 = enc4(v.w * inv);
  zn4[(size_t)row * 64 + lane] =
      (unsigned short)(n0 | (n1 << 4) | (n2 << 8) | (n3 << 12));
}

__global__ __launch_bounds__(256, 4) void gram_kernel(const unsigned short* __restrict__ zn4,
                                                      float* __restrict__ rowp,
                                                      float* __restrict__ colp,
                                                      float* __restrict__ ppos) {
  __shared__ __align__(16) char bt[2 * 64 * 128];  // double-buffered fp4 B panels
  __shared__ float colLDS[4][256];                 // per-wave col partials
  const int tid = threadIdx.x;
  const int w = tid >> 6, l = tid & 63;
  const int lm = l & 15, hh = l >> 4;

  // decode linear block -> (bi, bj) with bj >= bi/2. C(bi)=p(65-p)+(bi&1)(32-p)
  const int L = blockIdx.x;
  int p = (int)((65.0f - sqrtf(4225.0f - 4.0f * (float)L)) * 0.5f);
  if (p < 0) p = 0;
  while (p < 32 && (p + 1) * (65 - (p + 1)) <= L) ++p;
  while (p > 0 && p * (65 - p) > L) --p;
  int r = L - p * (65 - p);
  int bi, bj;
  if (r < 32 - p) { bi = 2 * p; bj = p + r; }
  else            { bi = 2 * p + 1; bj = p + (r - (32 - p)); }

  const int r0w = bi * 128 + w * 32;  // this wave's 32 i-rows
  const int jbase = bj * 256;
  const char* znb = reinterpret_cast<const char*>(zn4);

  auto stage = [&](int s, int bfi) {
    const char* gs = znb + (size_t)(jbase + s * 64) * 128;
    char* base = bt + bfi * 8192 + w * 1024;
#pragma unroll
    for (int q = 0; q < 2; ++q) {
      int rloc = q * 32 + w * 8 + (l >> 3);
      int d = l & 7;
      const char* g = gs + (size_t)rloc * 128 + ((d ^ (rloc & 7)) << 4);
      __builtin_amdgcn_global_load_lds(
          (const __attribute__((address_space(1))) void*)g,
          (__attribute__((address_space(3))) void*)(base + q * 4096), 16, 0, 0);
    }
  };

  stage(0, 0);

  i32x8 a[2][2];
#pragma unroll
  for (int rf = 0; rf < 2; ++rf)
#pragma unroll
    for (int sl = 0; sl < 2; ++sl)
      a[rf][sl] = ld16z(znb + (size_t)(r0w + rf * 16 + lm) * 128 + sl * 64 + hh * 16);

  float sume[2][4];
#pragma unroll
  for (int rf = 0; rf < 2; ++rf)
#pragma unroll
    for (int t = 0; t < 4; ++t) sume[rf][t] = 0.f;

  const int swz = (lm & 7) << 4;

  auto readS = [&](const char* bp, int jt, int sl, i32x8& b) {
    const char* row = bp + (jt * 16 + lm) * 128;
    int cs = (sl * 64 + hh * 16) ^ swz;
    b = ld16z(row + cs);
  };

  if (bj > (bi >> 1)) {
    // ---------- FAST PATH: every tile strictly upper (94% of blocks) ----------
    f32x4 acA[2], acB[2];
    int pjtb = -1, pcol = 0;

    auto epiF = [&](const f32x4 (&pa)[2], int jtb, int pc) {
      float csum = 0.f;
#pragma unroll
      for (int rf = 0; rf < 2; ++rf) {
        const int itb = r0w + rf * 16;
        const bool ps = ((itb ^ B_HALF) == jtb);
#pragma unroll
        for (int t = 0; t < 4; ++t) {
          float sv = pa[rf][t];
          float e = fexp2(sv);
          sume[rf][t] += e;
          csum += e;
          if (ps && (lm == hh * 4 + t)) {  // positive pair: fill both halves
            ppos[itb + hh * 4 + t] = sv * RES_SCALE;
            ppos[jtb + lm] = sv * RES_SCALE;
          }
        }
      }
      csum += __shfl_xor(csum, 16);
      csum += __shfl_xor(csum, 32);
      if (hh == 0) colLDS[w][pc + lm] = csum;
    };

    for (int s = 0; s < NSTEP; ++s) {
      __syncthreads();
      if (s + 1 < NSTEP) stage(s + 1, (s + 1) & 1);
      const char* bp = bt + (s & 1) * 8192;
      i32x8 b[8];
#pragma unroll
      for (int u = 0; u < 8; ++u) readS(bp, u >> 1, u & 1, b[u]);

#pragma unroll
      for (int jt = 0; jt < 4; ++jt) {
        f32x4(&acc)[2] = (jt & 1) ? acB : acA;
        f32x4(&prev)[2] = (jt & 1) ? acA : acB;
        if (pjtb >= 0) epiF(prev, pjtb, pcol);
#pragma unroll
        for (int rf = 0; rf < 2; ++rf) acc[rf] = (f32x4){0.f, 0.f, 0.f, 0.f};
        __builtin_amdgcn_s_setprio(1);
#pragma unroll
        for (int rf = 0; rf < 2; ++rf) {
          acc[rf] = __builtin_amdgcn_mfma_scale_f32_16x16x128_f8f6f4(
              a[rf][0], b[jt * 2], acc[rf], 4, 4, 0, S4, 0, S4);
          acc[rf] = __builtin_amdgcn_mfma_scale_f32_16x16x128_f8f6f4(
              a[rf][1], b[jt * 2 + 1], acc[rf], 4, 4, 0, S4, 0, S4);
        }
        __builtin_amdgcn_s_setprio(0);
        pjtb = jbase + s * 64 + jt * 16;
        pcol = s * 64 + jt * 16;
      }
    }
    epiF(acB, pjtb, pcol);  // last tile was jt=3 -> acB
  } else {
    // ---------- SLOW PATH: straddling blocks (bj == bi>>1), 64 of 1056 -------
    // per-rf skip below diagonal, self-mask on diagonal; no positives here.
    for (int s = 0; s < NSTEP; ++s) {
      __syncthreads();
      if (s + 1 < NSTEP) stage(s + 1, (s + 1) & 1);
      const char* bp = bt + (s & 1) * 8192;
      i32x8 b[8];
#pragma unroll
      for (int u = 0; u < 8; ++u) readS(bp, u >> 1, u & 1, b[u]);

#pragma unroll
      for (int jt = 0; jt < 4; ++jt) {
        const int jtb = jbase + s * 64 + jt * 16;
        float csum = 0.f;
        f32x4 acc[2];
#pragma unroll
        for (int rf = 0; rf < 2; ++rf) acc[rf] = (f32x4){0.f, 0.f, 0.f, 0.f};
#pragma unroll
        for (int rf = 0; rf < 2; ++rf) {
          const int itb = r0w + rf * 16;
          if (jtb >= itb) {  // wave-uniform
            acc[rf] = __builtin_amdgcn_mfma_scale_f32_16x16x128_f8f6f4(
                a[rf][0], b[jt * 2], acc[rf], 4, 4, 0, S4, 0, S4);
            acc[rf] = __builtin_amdgcn_mfma_scale_f32_16x16x128_f8f6f4(
                a[rf][1], b[jt * 2 + 1], acc[rf], 4, 4, 0, S4, 0, S4);
          }
        }
#pragma unroll
        for (int rf = 0; rf < 2; ++rf) {
          const int itb = r0w + rf * 16;
          if (jtb < itb) continue;
          if (jtb == itb) {  // diagonal: rows only, mask self
#pragma unroll
            for (int t = 0; t < 4; ++t) {
              float e = fexp2(acc[rf][t]);
              if (lm == hh * 4 + t) e = 0.f;
              sume[rf][t] += e;
            }
          } else {  // upper: rows + cols
#pragma unroll
            for (int t = 0; t < 4; ++t) {
              float e = fexp2(acc[rf][t]);
              sume[rf][t] += e;
              csum += e;
            }
          }
        }
        csum += __shfl_xor(csum, 16);
        csum += __shfl_xor(csum, 32);
        if (hh == 0) colLDS[w][s * 64 + jt * 16 + lm] = csum;
      }
    }
  }

  // row partials -> slot bj
#pragma unroll
  for (int rf = 0; rf < 2; ++rf)
#pragma unroll
    for (int t = 0; t < 4; ++t) {
      float v = sume[rf][t];
#pragma unroll
      for (int m = 1; m < 16; m <<= 1) v += __shfl_xor(v, m);
      if (lm == 0) rowp[(size_t)bj * N_TOT + r0w + rf * 16 + hh * 4 + t] = v;
    }

  // col partials -> slot bi (4-wave combine)
  __syncthreads();
  float cs = colLDS[0][tid] + colLDS[1][tid] + colLDS[2][tid] + colLDS[3][tid];
  colp[(size_t)bi * N_TOT + jbase + tid] = cs;
}

__global__ __launch_bounds__(256) void fin1_kernel(const float* __restrict__ rowp,
                                                   const float* __restrict__ colp,
                                                   const float* __restrict__ ppos,
                                                   float* __restrict__ partial) {
  const int bx = blockIdx.x;           // 256-col panel == i>>8 for its rows
  const int i = bx * 256 + threadIdx.x;
  float se = 0.f;
  for (int s = bx; s < NROWP; ++s) se += rowp[(size_t)s * N_TOT + i];      // bj >= i>>8
  for (int s = 0; s <= 2 * bx + 1; ++s) se += colp[(size_t)s * N_TOT + i]; // bi <= 2bj+1
  float acc = logf(se) - ppos[i];
#pragma unroll
  for (int m = 32; m >= 1; m >>= 1) acc += __shfl_xor(acc, m);
  __shared__ float red[4];
  if ((threadIdx.x & 63) == 0) red[threadIdx.x >> 6] = acc;
  __syncthreads();
  if (threadIdx.x == 0) partial[bx] = red[0] + red[1] + red[2] + red[3];
}

__global__ void fin2_kernel(const float* __restrict__ partial, float* __restrict__ out) {
  float v = (threadIdx.x < 32) ? partial[threadIdx.x] : 0.f;
#pragma unroll
  for (int m = 32; m >= 1; m >>= 1) v += __shfl_xor(v, m);
  if (threadIdx.x == 0) out[0] = v / (float)N_TOT;
}

extern "C" void kernel_launch(void* const* d_in, const int* in_sizes, int n_in,
                              void* d_out, int out_size, void* d_ws, size_t ws_size,
                              hipStream_t stream) {
  const float* z1 = (const float*)d_in[0];
  const float* z2 = (const float*)d_in[1];
  float* out = (float*)d_out;
  char* ws = (char*)d_ws;

  unsigned short* zn4 = (unsigned short*)ws;         // 8192*128B = 1 MiB fp4
  float* rowp = (float*)(ws + (size_t)N_TOT * 128);  // 32*8192 f32 = 1 MiB
  float* colp = rowp + (size_t)NROWP * N_TOT;        // 64*8192 f32 = 2 MiB
  float* ppos = colp + (size_t)NCOLP * N_TOT;        // 8192 f32
  float* partial = ppos + N_TOT;                     // 32 f32

  nrm_kernel<<<N_TOT / 4, 256, 0, stream>>>(z1, z2, zn4);
  gram_kernel<<<NBLK, 256, 0, stream>>>(zn4, rowp, colp, ppos);
  fin1_kernel<<<N_TOT / 256, 256, 0, stream>>>(rowp, colp, ppos, partial);
  fin2_kernel<<<1, 64, 0, stream>>>(partial, out);
}

// Round 16
// 31.508 us; speedup vs baseline: 1.3704x; 1.3704x over previous
//
#include <hip/hip_runtime.h>
#include <hip/hip_bf16.h>

// NT-Xent loss, MI355X. B=4096, D=256, N=8192, temp=0.5.
// R16 = R13/R14 (MX-fp4, 4 waves/SIMD, zero-tail grid, full-step b[8]
// preload, deferred ping-pong epilogue) with the MFMA shape switched
// 16x16x128 -> 32x32x64: 9099 vs 7228 TF (m59/m25) and HALF the per-step
// instruction stream (8 MFMA vs 16, same 8 ds_read_b128, same exp count).
// Wave = 32 rows x (2 j-tiles of 32 cols)/step. C/D: col=l&31,
// row=(t&3)+8*(t>>2)+4*(l>>5) (m74/m101; dtype-independent). Tiles are
// 32-aligned and B%32==0, so diag/pos masks reduce to col==row.
// R15 lesson: symmetry halving loses to its own bookkeeping (2 designs,
// both regressed) - reverted. R5-R15 scoreboard: only pole shrinks pay.

typedef __attribute__((ext_vector_type(4))) float f32x4;
typedef __attribute__((ext_vector_type(16))) float f32x16;
typedef __attribute__((ext_vector_type(8))) int i32x8;

#define N_TOT 8192
#define B_HALF 4096
#define D_DIM 256
#define JSPLIT 16
#define JCOLS 512
#define NSTEP 8
#define SCL_PRE 1.6986436f             // sqrt((1/T)*log2 e)
#define RES_SCALE 0.6931471805599453f  // ln2: sim = acc * ln2 after prescale
#define S4 0x7B7B7B7B                  // E8M0 123 -> 2^-4 per operand

__device__ inline float fexp2(float x) {
#if __has_builtin(__builtin_amdgcn_exp2f)
  return __builtin_amdgcn_exp2f(x);  // raw v_exp_f32; args in [-3.2, 3.2]
#else
  return exp2f(x);
#endif
}

// e2m1 encode, RNE against grid {0,.5,1,1.5,2,3,4,6}, clamp at 6
__device__ inline unsigned enc4(float v) {
  float av = fabsf(v);
  unsigned c = (av >= 0.25f) + (av >= 0.75f) + (av >= 1.25f) + (av >= 1.75f) +
               (av >= 2.5f) + (av >= 3.5f) + (av >= 5.0f);
  return c | ((v < 0.f) ? 8u : 0u);
}

__device__ inline i32x8 ld16z(const char* p) {
  int4 lo = *reinterpret_cast<const int4*>(p);
  i32x8 r = {lo.x, lo.y, lo.z, lo.w, 0, 0, 0, 0};  // fp4 uses low 4 regs
  return r;
}

__global__ __launch_bounds__(256) void nrm_kernel(const float* __restrict__ z1,
                                                  const float* __restrict__ z2,
                                                  unsigned short* __restrict__ zn4) {
  int row = blockIdx.x * 4 + (threadIdx.x >> 6);
  int lane = threadIdx.x & 63;
  const float* src = (row < B_HALF) ? (z1 + (size_t)row * D_DIM)
                                    : (z2 + (size_t)(row - B_HALF) * D_DIM);
  f32x4 v = *reinterpret_cast<const f32x4*>(src + lane * 4);
  float ss = v.x * v.x + v.y * v.y + v.z * v.z + v.w * v.w;
#pragma unroll
  for (int m = 32; m >= 1; m >>= 1) ss += __shfl_xor(ss, m);
  // normalize + exp2 prescale + fp4 grid fill (x16, compensated by S4 scales)
  float inv = (SCL_PRE * 16.0f) / fmaxf(sqrtf(ss), 1e-8f);
  unsigned n0 = enc4(v.x * inv), n1 = enc4(v.y * inv);
  unsigned n2 = enc4(v.z * inv), n3 = enc4(v.w * inv);
  zn4[(size_t)row * 64 + lane] =
      (unsigned short)(n0 | (n1 << 4) | (n2 << 8) | (n3 << 12));
}

__global__ __launch_bounds__(256, 4) void gram_kernel(const unsigned short* __restrict__ zn4,
                                                      float* __restrict__ psum,
                                                      float* __restrict__ ppos) {
  __shared__ __align__(16) char bt[2 * 64 * 128];  // double-buffered fp4 B panels
  const int tid = threadIdx.x;
  const int w = tid >> 6, l = tid & 63;
  const int lm2 = l & 31, hh2 = l >> 5;       // 32x32 fragment coords
  const int r0w = blockIdx.x * 128 + w * 32;  // this wave's 32 i-rows
  const int jbase = blockIdx.y * JCOLS;
  const char* znb = reinterpret_cast<const char*>(zn4);

  // stage step s (64 B-rows x 128B fp4) into buffer bi (unchanged from R13)
  auto stage = [&](int s, int bfi) {
    const char* gs = znb + (size_t)(jbase + s * 64) * 128;
    char* base = bt + bfi * 8192 + w * 1024;
#pragma unroll
    for (int q = 0; q < 2; ++q) {
      int rloc = q * 32 + w * 8 + (l >> 3);
      int d = l & 7;  // dest 16B unit within the row
      const char* g = gs + (size_t)rloc * 128 + ((d ^ (rloc & 7)) << 4);
      __builtin_amdgcn_global_load_lds(
          (const __attribute__((address_space(1))) void*)g,
          (__attribute__((address_space(3))) void*)(base + q * 4096), 16, 0, 0);
    }
  };

  stage(0, 0);  // prefetch first panel; overlaps the A-fragment loads below

  // A fragments: 32 rows x K=256 fp4. 32x32x64 A map: row=l&31, k-half=l>>5.
  // lane: row lm2, slice sl (K=64): bytes sl*32 + hh2*16 .. +15.
  // B mirrors this (Gram symmetry -> k-permutations cancel).
  i32x8 a[4];
#pragma unroll
  for (int sl = 0; sl < 4; ++sl)
    a[sl] = ld16z(znb + (size_t)(r0w + lm2) * 128 + sl * 32 + hh2 * 16);

  float sume[16];
#pragma unroll
  for (int t = 0; t < 16; ++t) sume[t] = 0.f;

  const int swz = (lm2 & 7) << 4;  // panel row = jt*32+lm2 -> row&7 == lm2&7

  f32x16 acA, acB;  // ping-pong accumulators (static indexing)
  int pjtb = -1;

  // read one B slice: 32 cols x K=64 = 16B/lane, one swizzled ds_read_b128
  auto readS = [&](const char* bp, int jt, int sl, i32x8& b) {
    const char* row = bp + (jt * 32 + lm2) * 128;
    int cs = (sl * 32 + hh2 * 16) ^ swz;
    b = ld16z(row + cs);
  };

  // epilogue of a finished 32x32 tile: exp + LSE partial + diag/pos masks
  auto epilogue = [&](const f32x16& pa, int jtb) {
    const bool dg = (r0w == jtb);
    const bool ps = ((r0w ^ B_HALF) == jtb);
    if (dg | ps) {  // wave-uniform; rare special tiles
#pragma unroll
      for (int t = 0; t < 16; ++t) {
        float sv = pa[t];
        float e = fexp2(sv);
        int crow = (t & 3) + 8 * (t >> 2) + 4 * hh2;  // C/D row
        bool self = (lm2 == crow);                    // col == row
        if (dg && self) e = 0.f;                      // mask diagonal
        sume[t] += e;
        if (ps && self) ppos[r0w + crow] = sv * RES_SCALE;
      }
    } else {
#pragma unroll
      for (int t = 0; t < 16; ++t) sume[t] += fexp2(pa[t]);
    }
  };

  auto mfma_tile = [&](f32x16& acc, const i32x8* b) {
    __builtin_amdgcn_s_setprio(1);
#pragma unroll
    for (int sl = 0; sl < 4; ++sl)
      acc = __builtin_amdgcn_mfma_scale_f32_32x32x64_f8f6f4(
          a[sl], b[sl], acc, 4, 4, 0, S4, 0, S4);  // fmt 4 = FP4
    __builtin_amdgcn_s_setprio(0);
  };

  for (int s = 0; s < NSTEP; ++s) {
    __syncthreads();  // drains my stage loads + all waves done w/ prev buf
    if (s + 1 < NSTEP) stage(s + 1, (s + 1) & 1);  // async prefetch under compute
    const char* bp = bt + (s & 1) * 8192;

    // FULL-STEP preload: 2 tiles x 4 slices = 8 ds_read_b128 in flight
    i32x8 b[8];
#pragma unroll
    for (int u = 0; u < 8; ++u) readS(bp, u >> 2, u & 3, b[u]);

    // tile 0 (ping: acA), previous tile's epilogue under the read latency
    if (pjtb >= 0) epilogue(acB, pjtb);
    acA = (f32x16){0.f, 0.f, 0.f, 0.f, 0.f, 0.f, 0.f, 0.f,
                   0.f, 0.f, 0.f, 0.f, 0.f, 0.f, 0.f, 0.f};
    mfma_tile(acA, &b[0]);

    // tile 1 (pong: acB)
    epilogue(acA, jbase + s * 64);
    acB = (f32x16){0.f, 0.f, 0.f, 0.f, 0.f, 0.f, 0.f, 0.f,
                   0.f, 0.f, 0.f, 0.f, 0.f, 0.f, 0.f, 0.f};
    mfma_tile(acB, &b[4]);
    pjtb = jbase + s * 64 + 32;
  }
  epilogue(acB, pjtb);  // drain the last tile

  // reduce partial sums across the 32 col-lanes sharing each row-half
#pragma unroll
  for (int t = 0; t < 16; ++t) {
    float v = sume[t];
#pragma unroll
    for (int m = 1; m < 32; m <<= 1) v += __shfl_xor(v, m);
    if (lm2 == 0) {
      int crow = (t & 3) + 8 * (t >> 2) + 4 * hh2;
      psum[(size_t)blockIdx.y * N_TOT + r0w + crow] = v;
    }
  }
}

__global__ __launch_bounds__(256) void fin1_kernel(const float* __restrict__ psum,
                                                   const float* __restrict__ ppos,
                                                   float* __restrict__ partial) {
  int i = blockIdx.x * 256 + threadIdx.x;
  float se = 0.f;
#pragma unroll
  for (int s = 0; s < JSPLIT; ++s) se += psum[(size_t)s * N_TOT + i];
  float acc = logf(se) - ppos[i];
#pragma unroll
  for (int m = 32; m >= 1; m >>= 1) acc += __shfl_xor(acc, m);
  __shared__ float red[4];
  if ((threadIdx.x & 63) == 0) red[threadIdx.x >> 6] = acc;
  __syncthreads();
  if (threadIdx.x == 0) partial[blockIdx.x] = red[0] + red[1] + red[2] + red[3];
}

__global__ void fin2_kernel(const float* __restrict__ partial, float* __restrict__ out) {
  float v = (threadIdx.x < 32) ? partial[threadIdx.x] : 0.f;
#pragma unroll
  for (int m = 32; m >= 1; m >>= 1) v += __shfl_xor(v, m);
  if (threadIdx.x == 0) out[0] = v / (float)N_TOT;
}

extern "C" void kernel_launch(void* const* d_in, const int* in_sizes, int n_in,
                              void* d_out, int out_size, void* d_ws, size_t ws_size,
                              hipStream_t stream) {
  const float* z1 = (const float*)d_in[0];
  const float* z2 = (const float*)d_in[1];
  float* out = (float*)d_out;
  char* ws = (char*)d_ws;

  unsigned short* zn4 = (unsigned short*)ws;         // 8192*128B = 1 MiB fp4
  float* psum = (float*)(ws + (size_t)N_TOT * 128);  // 16*8192 f32
  float* ppos = psum + (size_t)JSPLIT * N_TOT;       // 8192 f32
  float* partial = ppos + N_TOT;                     // 32 f32

  nrm_kernel<<<N_TOT / 4, 256, 0, stream>>>(z1, z2, zn4);
  gram_kernel<<<dim3(N_TOT / 128, JSPLIT), 256, 0, stream>>>(zn4, psum, ppos);
  fin1_kernel<<<N_TOT / 256, 256, 0, stream>>>(psum, ppos, partial);
  fin2_kernel<<<1, 64, 0, stream>>>(partial, out);
}

// Round 17
// 30.351 us; speedup vs baseline: 1.4227x; 1.0381x over previous
//
#include <hip/hip_runtime.h>
#include <hip/hip_bf16.h>

// NT-Xent loss, MI355X. B=4096, D=256, N=8192, temp=0.5.
// R17 = exact revert to R13 (best verified: 29.8us total).
// R13 = MX-fp4 e2m1 (x16 encode, 2^-4 E8M0 scale pair), 16x16x128 MFMA,
// 32-row waves, 4 waves/SIMD ((256,4), ~115 live regs), 128x512 blocks,
// zero-tail 1024-block grid, LDS-staged B panels (global_load_lds,
// pre-swizzled source), depth-2 reg dbuf + deferred ping-pong epilogue.
// Scoreboard R4-R16: pole shrinks paid (occupancy +21%, fp8 +27%, fp4 +15%,
// 4w/SIMD +4%); ALL scheduling moves <=5%; symmetry halving regressed twice;
// 32x32 shape regressed; B-direct-from-global regressed. Residual ~5us of
// exposure in gram survived 6 structural attacks -> this is the structure's
// measured limit (poles: LDS 5.1 + MFMA 4.8 + trans 3.4 + VALU ~3 us).

typedef __attribute__((ext_vector_type(4))) float f32x4;
typedef __attribute__((ext_vector_type(8))) int i32x8;

#define N_TOT 8192
#define B_HALF 4096
#define D_DIM 256
#define JSPLIT 16
#define JCOLS 512
#define NSTEP 8
#define SCL_PRE 1.6986436f             // sqrt((1/T)*log2 e) = sqrt(2.8853901)
#define RES_SCALE 0.6931471805599453f  // ln2: sim = acc * ln2 after prescale
#define S4 0x7B7B7B7B                  // E8M0 123 -> 2^-4 per operand

__device__ inline float fexp2(float x) {
#if __has_builtin(__builtin_amdgcn_exp2f)
  return __builtin_amdgcn_exp2f(x);  // raw v_exp_f32; args in [-3.2, 3.2]
#else
  return exp2f(x);
#endif
}

// e2m1 encode, RNE against grid {0,.5,1,1.5,2,3,4,6}, clamp at 6
__device__ inline unsigned enc4(float v) {
  float av = fabsf(v);
  unsigned c = (av >= 0.25f) + (av >= 0.75f) + (av >= 1.25f) + (av >= 1.75f) +
               (av >= 2.5f) + (av >= 3.5f) + (av >= 5.0f);
  return c | ((v < 0.f) ? 8u : 0u);
}

__device__ inline i32x8 ld16z(const char* p) {
  int4 lo = *reinterpret_cast<const int4*>(p);
  i32x8 r = {lo.x, lo.y, lo.z, lo.w, 0, 0, 0, 0};  // fp4 uses low 4 regs
  return r;
}

__global__ __launch_bounds__(256) void nrm_kernel(const float* __restrict__ z1,
                                                  const float* __restrict__ z2,
                                                  unsigned short* __restrict__ zn4) {
  int row = blockIdx.x * 4 + (threadIdx.x >> 6);
  int lane = threadIdx.x & 63;
  const float* src = (row < B_HALF) ? (z1 + (size_t)row * D_DIM)
                                    : (z2 + (size_t)(row - B_HALF) * D_DIM);
  f32x4 v = *reinterpret_cast<const f32x4*>(src + lane * 4);
  float ss = v.x * v.x + v.y * v.y + v.z * v.z + v.w * v.w;
#pragma unroll
  for (int m = 32; m >= 1; m >>= 1) ss += __shfl_xor(ss, m);
  // normalize + exp2 prescale + fp4 grid fill (x16, compensated by S4 scales)
  float inv = (SCL_PRE * 16.0f) / fmaxf(sqrtf(ss), 1e-8f);
  unsigned n0 = enc4(v.x * inv), n1 = enc4(v.y * inv);
  unsigned n2 = enc4(v.z * inv), n3 = enc4(v.w * inv);
  zn4[(size_t)row * 64 + lane] =
      (unsigned short)(n0 | (n1 << 4) | (n2 << 8) | (n3 << 12));
}

__global__ __launch_bounds__(256, 4) void gram_kernel(const unsigned short* __restrict__ zn4,
                                                      float* __restrict__ psum,
                                                      float* __restrict__ ppos) {
  __shared__ __align__(16) char bt[2 * 64 * 128];  // double-buffered fp4 B panels
  const int tid = threadIdx.x;
  const int w = tid >> 6, l = tid & 63;
  const int lm = l & 15, hh = l >> 4;
  const int r0w = blockIdx.x * 128 + w * 32;  // this wave's 32 i-rows
  const int jbase = blockIdx.y * JCOLS;
  const char* znb = reinterpret_cast<const char*>(zn4);

  // stage step s (64 B-rows x 128B fp4) into buffer bi. LDS dest linear
  // (uniform base + lane*16); swizzle via XOR on the global source unit.
  auto stage = [&](int s, int bi) {
    const char* gs = znb + (size_t)(jbase + s * 64) * 128;
    char* base = bt + bi * 8192 + w * 1024;
#pragma unroll
    for (int q = 0; q < 2; ++q) {
      int rloc = q * 32 + w * 8 + (l >> 3);
      int d = l & 7;  // dest 16B unit within the row
      const char* g = gs + (size_t)rloc * 128 + ((d ^ (rloc & 7)) << 4);
      __builtin_amdgcn_global_load_lds(
          (const __attribute__((address_space(1))) void*)g,
          (__attribute__((address_space(3))) void*)(base + q * 4096), 16, 0, 0);
    }
  };

  stage(0, 0);  // prefetch first panel; overlaps the A-fragment loads below

  // A fragments: 32 rows x K=256 fp4 in registers. lane: row lm (+rf*16),
  // k-bytes sl*64 + hh*16 .. +15. B mirrors this (Gram symmetry).
  i32x8 a[2][2];
#pragma unroll
  for (int rf = 0; rf < 2; ++rf)
#pragma unroll
    for (int sl = 0; sl < 2; ++sl)
      a[rf][sl] = ld16z(znb + (size_t)(r0w + rf * 16 + lm) * 128 + sl * 64 + hh * 16);

  float sume[2][4];
#pragma unroll
  for (int rf = 0; rf < 2; ++rf)
#pragma unroll
    for (int t = 0; t < 4; ++t) sume[rf][t] = 0.f;

  const int swz = (lm & 7) << 4;  // row = jt*16+lm -> row&7 == lm&7

  i32x8 bh0, bh1;        // register-double-buffered B slices (K=128 each)
  f32x4 acA[2], acB[2];  // ping-pong accumulators (static indexing)
  int pjtb = -1;

  // read one B slice: 16 cols x K=128 = 16B/lane, one swizzled ds_read_b128
  auto readS = [&](const char* bp, int jt, int sl, i32x8& b) {
    const char* row = bp + (jt * 16 + lm) * 128;
    int cs = (sl * 64 + hh * 16) ^ swz;
    b = ld16z(row + cs);
  };

  // epilogue of a finished tile: exp + LSE partial + diag mask + positive
  auto epilogue = [&](const f32x4 (&pa)[2], int jtb) {
#pragma unroll
    for (int rf = 0; rf < 2; ++rf) {
      const int itb = r0w + rf * 16;
      const bool dg = (itb == jtb);
      const bool ps = ((itb ^ B_HALF) == jtb);
      if (dg | ps) {  // wave-uniform; rare special tiles
#pragma unroll
        for (int t = 0; t < 4; ++t) {
          float sv = pa[rf][t];
          float e = fexp2(sv);
          bool self = (lm == hh * 4 + t);  // C/D map: row=hh*4+t, col=lm
          if (dg && self) e = 0.f;         // mask diagonal
          sume[rf][t] += e;
          if (ps && self) ppos[itb + hh * 4 + t] = sv * RES_SCALE;
        }
      } else {
#pragma unroll
        for (int t = 0; t < 4; ++t) sume[rf][t] += fexp2(pa[rf][t]);
      }
    }
  };

  auto mfma2 = [&](f32x4 (&acc)[2], const i32x8& b, int sl) {
    __builtin_amdgcn_s_setprio(1);
#pragma unroll
    for (int rf = 0; rf < 2; ++rf)
      acc[rf] = __builtin_amdgcn_mfma_scale_f32_16x16x128_f8f6f4(
          a[rf][sl], b, acc[rf], 4, 4, 0, S4, 0, S4);  // fmt 4 = FP4
    __builtin_amdgcn_s_setprio(0);
  };

  for (int s = 0; s < NSTEP; ++s) {
    __syncthreads();  // drains my stage loads + all waves done w/ prev buf
    if (s + 1 < NSTEP) stage(s + 1, (s + 1) & 1);  // async prefetch under compute
    const char* bp = bt + (s & 1) * 8192;

    readS(bp, 0, 0, bh0);  // prologue: first slice of this step
#pragma unroll
    for (int jt = 0; jt < 4; ++jt) {
      f32x4(&acc)[2] = (jt & 1) ? acB : acA;
      f32x4(&prev)[2] = (jt & 1) ? acA : acB;

      readS(bp, jt, 1, bh1);                // in flight during epilogue+MFMA
      if (pjtb >= 0) epilogue(prev, pjtb);  // VALU/trans under read latency
#pragma unroll
      for (int rf = 0; rf < 2; ++rf) acc[rf] = (f32x4){0.f, 0.f, 0.f, 0.f};
      mfma2(acc, bh0, 0);
      if (jt < 3) readS(bp, jt + 1, 0, bh0);  // in flight during MFMA(bh1)
      mfma2(acc, bh1, 1);
      pjtb = jbase + s * 64 + jt * 16;
    }
  }
  epilogue(acB, pjtb);  // last tile was jt=3 -> acB

  // reduce partial sums across the 16 lanes (lm) sharing each row
#pragma unroll
  for (int rf = 0; rf < 2; ++rf)
#pragma unroll
    for (int t = 0; t < 4; ++t) {
      float v = sume[rf][t];
#pragma unroll
      for (int m = 1; m < 16; m <<= 1) v += __shfl_xor(v, m);
      if (lm == 0) psum[(size_t)blockIdx.y * N_TOT + r0w + rf * 16 + hh * 4 + t] = v;
    }
}

__global__ __launch_bounds__(256) void fin1_kernel(const float* __restrict__ psum,
                                                   const float* __restrict__ ppos,
                                                   float* __restrict__ partial) {
  int i = blockIdx.x * 256 + threadIdx.x;
  float se = 0.f;
#pragma unroll
  for (int s = 0; s < JSPLIT; ++s) se += psum[(size_t)s * N_TOT + i];
  float acc = logf(se) - ppos[i];
#pragma unroll
  for (int m = 32; m >= 1; m >>= 1) acc += __shfl_xor(acc, m);
  __shared__ float red[4];
  if ((threadIdx.x & 63) == 0) red[threadIdx.x >> 6] = acc;
  __syncthreads();
  if (threadIdx.x == 0) partial[blockIdx.x] = red[0] + red[1] + red[2] + red[3];
}

__global__ void fin2_kernel(const float* __restrict__ partial, float* __restrict__ out) {
  float v = (threadIdx.x < 32) ? partial[threadIdx.x] : 0.f;
#pragma unroll
  for (int m = 32; m >= 1; m >>= 1) v += __shfl_xor(v, m);
  if (threadIdx.x == 0) out[0] = v / (float)N_TOT;
}

extern "C" void kernel_launch(void* const* d_in, const int* in_sizes, int n_in,
                              void* d_out, int out_size, void* d_ws, size_t ws_size,
                              hipStream_t stream) {
  const float* z1 = (const float*)d_in[0];
  const float* z2 = (const float*)d_in[1];
  float* out = (float*)d_out;
  char* ws = (char*)d_ws;

  unsigned short* zn4 = (unsigned short*)ws;         // 8192*128B = 1 MiB fp4
  float* psum = (float*)(ws + (size_t)N_TOT * 128);  // 16*8192 f32
  float* ppos = psum + (size_t)JSPLIT * N_TOT;       // 8192 f32
  float* partial = ppos + N_TOT;                     // 32 f32

  nrm_kernel<<<N_TOT / 4, 256, 0, stream>>>(z1, z2, zn4);
  gram_kernel<<<dim3(N_TOT / 128, JSPLIT), 256, 0, stream>>>(zn4, psum, ppos);
  fin1_kernel<<<N_TOT / 256, 256, 0, stream>>>(psum, ppos, partial);
  fin2_kernel<<<1, 64, 0, stream>>>(partial, out);
}